// Round 1
// baseline (9710.178 us; speedup 1.0000x reference)
//
#include <hip/hip_runtime.h>
#include <hip/hip_bf16.h>

#define HW   65536
#define CHW  (128*65536)

__device__ __forceinline__ float geluf(float v){
    return 0.5f * v * (1.f + erff(v * 0.70710678118654752f));
}

// ---------------- K1: LN1 + QKV GEMM + gate(q) ----------------
// grid (4096, 3), block 256. oz: 0=q,1=k,2=v. Writes qkv f32 [B,384,HW] in ws.
__global__ __launch_bounds__(256) void k_ln_qkv(
    const float* __restrict__ x, const float* __restrict__ l0,
    const float* __restrict__ n1w, const float* __restrict__ n1b,
    const float* __restrict__ qkv_w, const float* __restrict__ gate_w,
    const float* __restrict__ gate_b, float* __restrict__ qkv)
{
    __shared__ float sx[64*129];
    __shared__ float red1[256];
    __shared__ float red2[256];
    __shared__ float smean[64];
    __shared__ float srstd[64];
    const int t = threadIdx.x;
    const int pbase = blockIdx.x * 64;
    const int oz = blockIdx.y;
    const int b = pbase >> 16;
    const int hw0 = pbase & 65535;
    const float* xb = x + (size_t)b*CHW + hw0;
    const int pix = t & 63, og = t >> 6;

    #pragma unroll
    for (int i = 0; i < 32; ++i) {
        int idx = t + i*256;
        int c = idx >> 6, p = idx & 63;
        sx[p*129 + c] = xb[(size_t)c*HW + p];
    }
    __syncthreads();
    // per-pixel LN stats: thread (pix, og) sums 32 channels
    float s1 = 0.f, s2 = 0.f;
    #pragma unroll
    for (int i = 0; i < 32; ++i) {
        float v = sx[pix*129 + og*32 + i];
        s1 += v; s2 += v*v;
    }
    red1[t] = s1; red2[t] = s2;   // t == og*64 + pix
    __syncthreads();
    if (t < 64) {
        float su = red1[t] + red1[t+64] + red1[t+128] + red1[t+192];
        float sq = red2[t] + red2[t+64] + red2[t+128] + red2[t+192];
        float mean = su * 0.0078125f;
        float var  = sq * 0.0078125f - mean*mean;
        smean[t] = mean;
        srstd[t] = 1.f / sqrtf(var + 1e-6f);
    }
    __syncthreads();
    #pragma unroll
    for (int i = 0; i < 32; ++i) {
        int idx = t + i*256;
        int c = idx >> 6, p = idx & 63;
        float v = sx[p*129 + c];
        sx[p*129 + c] = (v - smean[p]) * srstd[p] * n1w[c] + n1b[c];
    }
    __syncthreads();

    const float* Wb = qkv_w + (size_t)oz*128*128;
    float acc[32];
    #pragma unroll
    for (int j = 0; j < 32; ++j) acc[j] = 0.f;
    #pragma unroll 4
    for (int c0 = 0; c0 < 128; c0 += 4) {
        const float a0 = sx[pix*129 + c0];
        const float a1 = sx[pix*129 + c0 + 1];
        const float a2 = sx[pix*129 + c0 + 2];
        const float a3 = sx[pix*129 + c0 + 3];
        #pragma unroll
        for (int j = 0; j < 32; ++j) {
            const float4 w4 = *(const float4*)(Wb + (size_t)(og*32 + j)*128 + c0);
            acc[j] = fmaf(a0, w4.x, fmaf(a1, w4.y, fmaf(a2, w4.z, fmaf(a3, w4.w, acc[j]))));
        }
    }
    float* ob = qkv + (size_t)b*384*HW + (size_t)oz*128*HW + hw0;
    if (oz == 0) {
        const float lv = l0[(size_t)b*HW + hw0 + pix];
        #pragma unroll
        for (int j = 0; j < 32; ++j) {
            const int o = og*32 + j;
            const float g = 1.f / (1.f + __expf(-(lv*gate_w[o] + gate_b[o])));
            ob[(size_t)o*HW + pix] = acc[j] * g;
        }
    } else {
        #pragma unroll
        for (int j = 0; j < 32; ++j) {
            const int o = og*32 + j;
            ob[(size_t)o*HW + pix] = acc[j];
        }
    }
}

// ---------------- K2: windowed attention ----------------
// grid (4096, 8) = (windows, heads), block 64 (one wave). Writes attn out -> d_out.
__global__ __launch_bounds__(64) void k_attn(
    const float* __restrict__ qkv, float* __restrict__ attn_out)
{
    __shared__ float sk[64*17];
    __shared__ float sv[64*17];
    const int t = threadIdx.x;
    const int win = blockIdx.x;
    const int head = blockIdx.y;
    const int b = win >> 10;
    const int wi = win & 1023;
    const int wy = wi >> 5, wx = wi & 31;
    const int ty = t >> 3, tx = t & 7;
    const int y = wy*8 + ty, xx = wx*8 + tx;
    const size_t hw = (size_t)y*256 + xx;
    const float* qb = qkv + (size_t)b*384*HW + (size_t)head*16*HW + hw;
    const float* kb = qb + (size_t)128*HW;
    const float* vb = qb + (size_t)256*HW;
    float qr[16];
    #pragma unroll
    for (int d = 0; d < 16; ++d) {
        qr[d]       = qb[(size_t)d*HW];
        sk[t*17+d]  = kb[(size_t)d*HW];
        sv[t*17+d]  = vb[(size_t)d*HW];
    }
    __syncthreads();
    float sc[64];
    float m = -1e30f;
    #pragma unroll
    for (int kt = 0; kt < 64; ++kt) {
        float dot = 0.f;
        #pragma unroll
        for (int d = 0; d < 16; ++d) dot = fmaf(qr[d], sk[kt*17+d], dot);
        dot *= 0.25f;          // head_dim^-0.5
        sc[kt] = dot;
        m = fmaxf(m, dot);
    }
    float ssum = 0.f;
    #pragma unroll
    for (int kt = 0; kt < 64; ++kt) { float e = __expf(sc[kt]-m); sc[kt] = e; ssum += e; }
    const float rs = 1.f / ssum;
    float o[16];
    #pragma unroll
    for (int d = 0; d < 16; ++d) o[d] = 0.f;
    #pragma unroll
    for (int kt = 0; kt < 64; ++kt) {
        const float p = sc[kt];
        #pragma unroll
        for (int d = 0; d < 16; ++d) o[d] = fmaf(p, sv[kt*17+d], o[d]);
    }
    float* ob = attn_out + (size_t)b*CHW + (size_t)head*16*HW + hw;
    #pragma unroll
    for (int d = 0; d < 16; ++d) ob[(size_t)d*HW] = o[d]*rs;
}

// ---------------- K3: proj + bias + shortcut (in-place on d_out) ----------------
// grid 4096, block 256
__global__ __launch_bounds__(256) void k_proj(
    const float* __restrict__ x, const float* __restrict__ proj_w,
    const float* __restrict__ proj_b, float* __restrict__ out)
{
    __shared__ float sx[64*129];
    const int t = threadIdx.x;
    const int pbase = blockIdx.x * 64;
    const int b = pbase >> 16;
    const int hw0 = pbase & 65535;
    const float* ab = out + (size_t)b*CHW + hw0;
    #pragma unroll
    for (int i = 0; i < 32; ++i) {
        int idx = t + i*256;
        int c = idx >> 6, p = idx & 63;
        sx[p*129 + c] = ab[(size_t)c*HW + p];
    }
    __syncthreads();
    const int pix = t & 63, og = t >> 6;
    float acc[32];
    #pragma unroll
    for (int j = 0; j < 32; ++j) acc[j] = 0.f;
    #pragma unroll 4
    for (int c0 = 0; c0 < 128; c0 += 4) {
        const float a0 = sx[pix*129 + c0];
        const float a1 = sx[pix*129 + c0 + 1];
        const float a2 = sx[pix*129 + c0 + 2];
        const float a3 = sx[pix*129 + c0 + 3];
        #pragma unroll
        for (int j = 0; j < 32; ++j) {
            const float4 w4 = *(const float4*)(proj_w + (size_t)(og*32 + j)*128 + c0);
            acc[j] = fmaf(a0, w4.x, fmaf(a1, w4.y, fmaf(a2, w4.z, fmaf(a3, w4.w, acc[j]))));
        }
    }
    const float* xb = x + (size_t)b*CHW + hw0;
    float* ob = out + (size_t)b*CHW + hw0;
    #pragma unroll
    for (int j = 0; j < 32; ++j) {
        const int o = og*32 + j;
        ob[(size_t)o*HW + pix] = acc[j] + proj_b[o] + xb[(size_t)o*HW + pix];
    }
}

// ---------------- K4: LN2 + FFN1 GEMM + GELU -> h1 (bf16, in ws) ----------------
// grid (4096, 4), block 256
__global__ __launch_bounds__(256) void k_ffn1(
    const float* __restrict__ out, const float* __restrict__ n2w, const float* __restrict__ n2b,
    const float* __restrict__ w1, const float* __restrict__ b1,
    __hip_bfloat16* __restrict__ h1)
{
    __shared__ float sx[64*129];
    __shared__ float red1[256];
    __shared__ float red2[256];
    __shared__ float smean[64];
    __shared__ float srstd[64];
    const int t = threadIdx.x;
    const int pbase = blockIdx.x * 64;
    const int obase = blockIdx.y * 128;
    const int b = pbase >> 16;
    const int hw0 = pbase & 65535;
    const float* xb = out + (size_t)b*CHW + hw0;
    const int pix = t & 63, og = t >> 6;

    #pragma unroll
    for (int i = 0; i < 32; ++i) {
        int idx = t + i*256;
        int c = idx >> 6, p = idx & 63;
        sx[p*129 + c] = xb[(size_t)c*HW + p];
    }
    __syncthreads();
    float s1 = 0.f, s2 = 0.f;
    #pragma unroll
    for (int i = 0; i < 32; ++i) {
        float v = sx[pix*129 + og*32 + i];
        s1 += v; s2 += v*v;
    }
    red1[t] = s1; red2[t] = s2;
    __syncthreads();
    if (t < 64) {
        float su = red1[t] + red1[t+64] + red1[t+128] + red1[t+192];
        float sq = red2[t] + red2[t+64] + red2[t+128] + red2[t+192];
        float mean = su * 0.0078125f;
        float var  = sq * 0.0078125f - mean*mean;
        smean[t] = mean;
        srstd[t] = 1.f / sqrtf(var + 1e-6f);
    }
    __syncthreads();
    #pragma unroll
    for (int i = 0; i < 32; ++i) {
        int idx = t + i*256;
        int c = idx >> 6, p = idx & 63;
        float v = sx[p*129 + c];
        sx[p*129 + c] = (v - smean[p]) * srstd[p] * n2w[c] + n2b[c];
    }
    __syncthreads();

    float acc[32];
    #pragma unroll
    for (int j = 0; j < 32; ++j) acc[j] = 0.f;
    #pragma unroll 4
    for (int c0 = 0; c0 < 128; c0 += 4) {
        const float a0 = sx[pix*129 + c0];
        const float a1 = sx[pix*129 + c0 + 1];
        const float a2 = sx[pix*129 + c0 + 2];
        const float a3 = sx[pix*129 + c0 + 3];
        #pragma unroll
        for (int j = 0; j < 32; ++j) {
            const float4 w4 = *(const float4*)(w1 + (size_t)(obase + og*32 + j)*128 + c0);
            acc[j] = fmaf(a0, w4.x, fmaf(a1, w4.y, fmaf(a2, w4.z, fmaf(a3, w4.w, acc[j]))));
        }
    }
    __hip_bfloat16* hb = h1 + (size_t)b*512*HW + hw0;
    #pragma unroll
    for (int j = 0; j < 32; ++j) {
        const int o = obase + og*32 + j;
        const float v = geluf(acc[j] + b1[o]);
        hb[(size_t)o*HW + pix] = __float2bfloat16(v);
    }
}

// ---------------- K5: depthwise 3x3 + GELU + FFN2 GEMM + b2 + residual ----------------
// grid 4096, block 256. In-place accumulate into d_out.
__global__ __launch_bounds__(256) void k_ffn2(
    const __hip_bfloat16* __restrict__ h1, const float* __restrict__ dwf,
    const float* __restrict__ dwb, const float* __restrict__ w2,
    const float* __restrict__ b2, float* __restrict__ out)
{
    __shared__ __hip_bfloat16 shalo[64*198];  // [c][3 rows][66 cols]
    __shared__ float sconv[64*65];            // [c][64 pix + pad]
    const int t = threadIdx.x;
    const int pbase = blockIdx.x * 64;
    const int b = pbase >> 16;
    const int hw0 = pbase & 65535;
    const int row = hw0 >> 8;
    const int x0 = hw0 & 255;
    const int pix = t & 63, og = t >> 6;
    const __hip_bfloat16* h1b = h1 + (size_t)b*512*HW;
    float acc[32];
    #pragma unroll
    for (int j = 0; j < 32; ++j) acc[j] = 0.f;

    for (int cc = 0; cc < 8; ++cc) {
        const int cbase = cc*64;
        // stage halo [64c][3][66] (zero padded)
        for (int i = 0; i < 50; ++i) {
            int idx = t + i*256;
            if (idx < 12672) {
                int c = idx / 198;
                int rem = idx - c*198;
                int r = rem / 66;
                int ci = rem - r*66;
                int yy = row + r - 1;
                int xc = x0 + ci - 1;
                __hip_bfloat16 v = __float2bfloat16(0.f);
                if ((unsigned)yy < 256u && (unsigned)xc < 256u)
                    v = h1b[(size_t)(cbase+c)*HW + (size_t)yy*256 + xc];
                shalo[c*198 + r*66 + ci] = v;
            }
        }
        __syncthreads();
        // depthwise conv + dwb + gelu
        #pragma unroll
        for (int i = 0; i < 16; ++i) {
            int idx = t + i*256;
            int c = idx >> 6, p = idx & 63;
            const float* dwc = dwf + (size_t)(cbase + c)*9;
            float s = dwb[cbase + c];
            #pragma unroll
            for (int r = 0; r < 3; ++r)
                #pragma unroll
                for (int dx = 0; dx < 3; ++dx)
                    s = fmaf(__bfloat162float(shalo[c*198 + r*66 + p + dx]), dwc[r*3 + dx], s);
            sconv[c*65 + p] = geluf(s);
        }
        __syncthreads();
        // GEMM partial over this 64-channel chunk
        #pragma unroll 4
        for (int c0 = 0; c0 < 64; c0 += 4) {
            const float a0 = sconv[(c0+0)*65 + pix];
            const float a1 = sconv[(c0+1)*65 + pix];
            const float a2 = sconv[(c0+2)*65 + pix];
            const float a3 = sconv[(c0+3)*65 + pix];
            #pragma unroll
            for (int j = 0; j < 32; ++j) {
                const float4 w4 = *(const float4*)(w2 + (size_t)(og*32 + j)*512 + cbase + c0);
                acc[j] = fmaf(a0, w4.x, fmaf(a1, w4.y, fmaf(a2, w4.z, fmaf(a3, w4.w, acc[j]))));
            }
        }
        __syncthreads();
    }
    float* ob = out + (size_t)b*CHW + hw0;
    #pragma unroll
    for (int j = 0; j < 32; ++j) {
        const int o = og*32 + j;
        ob[(size_t)o*HW + pix] = acc[j] + b2[o] + ob[(size_t)o*HW + pix];
    }
}

extern "C" void kernel_launch(void* const* d_in, const int* in_sizes, int n_in,
                              void* d_out, int out_size, void* d_ws, size_t ws_size,
                              hipStream_t stream) {
    const float* x      = (const float*)d_in[0];
    const float* l0     = (const float*)d_in[1];
    const float* n1w    = (const float*)d_in[2];
    const float* n1b    = (const float*)d_in[3];
    const float* n2w    = (const float*)d_in[4];
    const float* n2b    = (const float*)d_in[5];
    const float* qkv_w  = (const float*)d_in[6];
    const float* gate_w = (const float*)d_in[7];
    const float* gate_b = (const float*)d_in[8];
    const float* proj_w = (const float*)d_in[9];
    const float* proj_b = (const float*)d_in[10];
    const float* ffn_w1 = (const float*)d_in[11];
    const float* ffn_b1 = (const float*)d_in[12];
    const float* ffn_dw = (const float*)d_in[13];
    const float* ffn_dwb= (const float*)d_in[14];
    const float* ffn_w2 = (const float*)d_in[15];
    const float* ffn_b2 = (const float*)d_in[16];

    float* out = (float*)d_out;
    float* qkv = (float*)d_ws;                       // [B,384,HW] f32 = 402.7 MB
    __hip_bfloat16* h1 = (__hip_bfloat16*)d_ws;      // [B,512,HW] bf16 = 268.4 MB, reuses qkv region

    k_ln_qkv<<<dim3(4096, 3), dim3(256), 0, stream>>>(x, l0, n1w, n1b, qkv_w, gate_w, gate_b, qkv);
    k_attn  <<<dim3(4096, 8), dim3(64),  0, stream>>>(qkv, out);
    k_proj  <<<dim3(4096, 1), dim3(256), 0, stream>>>(x, proj_w, proj_b, out);
    k_ffn1  <<<dim3(4096, 4), dim3(256), 0, stream>>>(out, n2w, n2b, ffn_w1, ffn_b1, h1);
    k_ffn2  <<<dim3(4096, 1), dim3(256), 0, stream>>>(h1, ffn_dw, ffn_dwb, ffn_w2, ffn_b2, out);
}

// Round 2
// 6344.380 us; speedup vs baseline: 1.5305x; 1.5305x over previous
//
#include <hip/hip_runtime.h>
#include <hip/hip_bf16.h>

#define HW   65536
#define CHW  (128*65536)

typedef __attribute__((ext_vector_type(8))) short bf16x8;
typedef __attribute__((ext_vector_type(4))) float f32x4;

__device__ __forceinline__ float geluf(float v){
    return 0.5f * v * (1.f + erff(v * 0.70710678118654752f));
}

// ---------------- K1: LN1 + QKV GEMM + gate(q) ----------------
__global__ __launch_bounds__(256) void k_ln_qkv(
    const float* __restrict__ x, const float* __restrict__ l0,
    const float* __restrict__ n1w, const float* __restrict__ n1b,
    const float* __restrict__ qkv_w, const float* __restrict__ gate_w,
    const float* __restrict__ gate_b, float* __restrict__ qkv)
{
    __shared__ float sx[64*129];
    __shared__ float red1[256];
    __shared__ float red2[256];
    __shared__ float smean[64];
    __shared__ float srstd[64];
    const int t = threadIdx.x;
    const int pbase = blockIdx.x * 64;
    const int oz = blockIdx.y;
    const int b = pbase >> 16;
    const int hw0 = pbase & 65535;
    const float* xb = x + (size_t)b*CHW + hw0;
    const int pix = t & 63, og = t >> 6;

    #pragma unroll
    for (int i = 0; i < 32; ++i) {
        int idx = t + i*256;
        int c = idx >> 6, p = idx & 63;
        sx[p*129 + c] = xb[(size_t)c*HW + p];
    }
    __syncthreads();
    float s1 = 0.f, s2 = 0.f;
    #pragma unroll
    for (int i = 0; i < 32; ++i) {
        float v = sx[pix*129 + og*32 + i];
        s1 += v; s2 += v*v;
    }
    red1[t] = s1; red2[t] = s2;
    __syncthreads();
    if (t < 64) {
        float su = red1[t] + red1[t+64] + red1[t+128] + red1[t+192];
        float sq = red2[t] + red2[t+64] + red2[t+128] + red2[t+192];
        float mean = su * 0.0078125f;
        float var  = sq * 0.0078125f - mean*mean;
        smean[t] = mean;
        srstd[t] = 1.f / sqrtf(var + 1e-6f);
    }
    __syncthreads();
    #pragma unroll
    for (int i = 0; i < 32; ++i) {
        int idx = t + i*256;
        int c = idx >> 6, p = idx & 63;
        float v = sx[p*129 + c];
        sx[p*129 + c] = (v - smean[p]) * srstd[p] * n1w[c] + n1b[c];
    }
    __syncthreads();

    const float* Wb = qkv_w + (size_t)oz*128*128;
    float acc[32];
    #pragma unroll
    for (int j = 0; j < 32; ++j) acc[j] = 0.f;
    #pragma unroll 4
    for (int c0 = 0; c0 < 128; c0 += 4) {
        const float a0 = sx[pix*129 + c0];
        const float a1 = sx[pix*129 + c0 + 1];
        const float a2 = sx[pix*129 + c0 + 2];
        const float a3 = sx[pix*129 + c0 + 3];
        #pragma unroll
        for (int j = 0; j < 32; ++j) {
            const float4 w4 = *(const float4*)(Wb + (size_t)(og*32 + j)*128 + c0);
            acc[j] = fmaf(a0, w4.x, fmaf(a1, w4.y, fmaf(a2, w4.z, fmaf(a3, w4.w, acc[j]))));
        }
    }
    float* ob = qkv + (size_t)b*384*HW + (size_t)oz*128*HW + hw0;
    if (oz == 0) {
        const float lv = l0[(size_t)b*HW + hw0 + pix];
        #pragma unroll
        for (int j = 0; j < 32; ++j) {
            const int o = og*32 + j;
            const float g = 1.f / (1.f + __expf(-(lv*gate_w[o] + gate_b[o])));
            ob[(size_t)o*HW + pix] = acc[j] * g;
        }
    } else {
        #pragma unroll
        for (int j = 0; j < 32; ++j) {
            const int o = og*32 + j;
            ob[(size_t)o*HW + pix] = acc[j];
        }
    }
}

// ---------------- K2: windowed attention ----------------
__global__ __launch_bounds__(64) void k_attn(
    const float* __restrict__ qkv, float* __restrict__ attn_out)
{
    __shared__ float sk[64*17];
    __shared__ float sv[64*17];
    const int t = threadIdx.x;
    const int win = blockIdx.x;
    const int head = blockIdx.y;
    const int b = win >> 10;
    const int wi = win & 1023;
    const int wy = wi >> 5, wx = wi & 31;
    const int ty = t >> 3, tx = t & 7;
    const int y = wy*8 + ty, xx = wx*8 + tx;
    const size_t hw = (size_t)y*256 + xx;
    const float* qb = qkv + (size_t)b*384*HW + (size_t)head*16*HW + hw;
    const float* kb = qb + (size_t)128*HW;
    const float* vb = qb + (size_t)256*HW;
    float qr[16];
    #pragma unroll
    for (int d = 0; d < 16; ++d) {
        qr[d]       = qb[(size_t)d*HW];
        sk[t*17+d]  = kb[(size_t)d*HW];
        sv[t*17+d]  = vb[(size_t)d*HW];
    }
    __syncthreads();
    float sc[64];
    float m = -1e30f;
    #pragma unroll
    for (int kt = 0; kt < 64; ++kt) {
        float dot = 0.f;
        #pragma unroll
        for (int d = 0; d < 16; ++d) dot = fmaf(qr[d], sk[kt*17+d], dot);
        dot *= 0.25f;
        sc[kt] = dot;
        m = fmaxf(m, dot);
    }
    float ssum = 0.f;
    #pragma unroll
    for (int kt = 0; kt < 64; ++kt) { float e = __expf(sc[kt]-m); sc[kt] = e; ssum += e; }
    const float rs = 1.f / ssum;
    float o[16];
    #pragma unroll
    for (int d = 0; d < 16; ++d) o[d] = 0.f;
    #pragma unroll
    for (int kt = 0; kt < 64; ++kt) {
        const float p = sc[kt];
        #pragma unroll
        for (int d = 0; d < 16; ++d) o[d] = fmaf(p, sv[kt*17+d], o[d]);
    }
    float* ob = attn_out + (size_t)b*CHW + (size_t)head*16*HW + hw;
    #pragma unroll
    for (int d = 0; d < 16; ++d) ob[(size_t)d*HW] = o[d]*rs;
}

// ---------------- K3: proj + bias + shortcut (in-place on d_out) ----------------
__global__ __launch_bounds__(256) void k_proj(
    const float* __restrict__ x, const float* __restrict__ proj_w,
    const float* __restrict__ proj_b, float* __restrict__ out)
{
    __shared__ float sx[64*129];
    const int t = threadIdx.x;
    const int pbase = blockIdx.x * 64;
    const int b = pbase >> 16;
    const int hw0 = pbase & 65535;
    const float* ab = out + (size_t)b*CHW + hw0;
    #pragma unroll
    for (int i = 0; i < 32; ++i) {
        int idx = t + i*256;
        int c = idx >> 6, p = idx & 63;
        sx[p*129 + c] = ab[(size_t)c*HW + p];
    }
    __syncthreads();
    const int pix = t & 63, og = t >> 6;
    float acc[32];
    #pragma unroll
    for (int j = 0; j < 32; ++j) acc[j] = 0.f;
    #pragma unroll 4
    for (int c0 = 0; c0 < 128; c0 += 4) {
        const float a0 = sx[pix*129 + c0];
        const float a1 = sx[pix*129 + c0 + 1];
        const float a2 = sx[pix*129 + c0 + 2];
        const float a3 = sx[pix*129 + c0 + 3];
        #pragma unroll
        for (int j = 0; j < 32; ++j) {
            const float4 w4 = *(const float4*)(proj_w + (size_t)(og*32 + j)*128 + c0);
            acc[j] = fmaf(a0, w4.x, fmaf(a1, w4.y, fmaf(a2, w4.z, fmaf(a3, w4.w, acc[j]))));
        }
    }
    const float* xb = x + (size_t)b*CHW + hw0;
    float* ob = out + (size_t)b*CHW + hw0;
    #pragma unroll
    for (int j = 0; j < 32; ++j) {
        const int o = og*32 + j;
        ob[(size_t)o*HW + pix] = acc[j] + proj_b[o] + xb[(size_t)o*HW + pix];
    }
}

// ---------------- K4: LN2 + FFN1 GEMM + GELU -> h1 (bf16, in ws) ----------------
__global__ __launch_bounds__(256) void k_ffn1(
    const float* __restrict__ out, const float* __restrict__ n2w, const float* __restrict__ n2b,
    const float* __restrict__ w1, const float* __restrict__ b1,
    __hip_bfloat16* __restrict__ h1)
{
    __shared__ float sx[64*129];
    __shared__ float red1[256];
    __shared__ float red2[256];
    __shared__ float smean[64];
    __shared__ float srstd[64];
    const int t = threadIdx.x;
    const int pbase = blockIdx.x * 64;
    const int obase = blockIdx.y * 128;
    const int b = pbase >> 16;
    const int hw0 = pbase & 65535;
    const float* xb = out + (size_t)b*CHW + hw0;
    const int pix = t & 63, og = t >> 6;

    #pragma unroll
    for (int i = 0; i < 32; ++i) {
        int idx = t + i*256;
        int c = idx >> 6, p = idx & 63;
        sx[p*129 + c] = xb[(size_t)c*HW + p];
    }
    __syncthreads();
    float s1 = 0.f, s2 = 0.f;
    #pragma unroll
    for (int i = 0; i < 32; ++i) {
        float v = sx[pix*129 + og*32 + i];
        s1 += v; s2 += v*v;
    }
    red1[t] = s1; red2[t] = s2;
    __syncthreads();
    if (t < 64) {
        float su = red1[t] + red1[t+64] + red1[t+128] + red1[t+192];
        float sq = red2[t] + red2[t+64] + red2[t+128] + red2[t+192];
        float mean = su * 0.0078125f;
        float var  = sq * 0.0078125f - mean*mean;
        smean[t] = mean;
        srstd[t] = 1.f / sqrtf(var + 1e-6f);
    }
    __syncthreads();
    #pragma unroll
    for (int i = 0; i < 32; ++i) {
        int idx = t + i*256;
        int c = idx >> 6, p = idx & 63;
        float v = sx[p*129 + c];
        sx[p*129 + c] = (v - smean[p]) * srstd[p] * n2w[c] + n2b[c];
    }
    __syncthreads();

    float acc[32];
    #pragma unroll
    for (int j = 0; j < 32; ++j) acc[j] = 0.f;
    #pragma unroll 4
    for (int c0 = 0; c0 < 128; c0 += 4) {
        const float a0 = sx[pix*129 + c0];
        const float a1 = sx[pix*129 + c0 + 1];
        const float a2 = sx[pix*129 + c0 + 2];
        const float a3 = sx[pix*129 + c0 + 3];
        #pragma unroll
        for (int j = 0; j < 32; ++j) {
            const float4 w4 = *(const float4*)(w1 + (size_t)(obase + og*32 + j)*128 + c0);
            acc[j] = fmaf(a0, w4.x, fmaf(a1, w4.y, fmaf(a2, w4.z, fmaf(a3, w4.w, acc[j]))));
        }
    }
    __hip_bfloat16* hb = h1 + (size_t)b*512*HW + hw0;
    #pragma unroll
    for (int j = 0; j < 32; ++j) {
        const int o = obase + og*32 + j;
        const float v = geluf(acc[j] + b1[o]);
        hb[(size_t)o*HW + pix] = __float2bfloat16(v);
    }
}

// ---------------- K4b: convert ffn_w2 to bf16 (into ws scratch) ----------------
__global__ __launch_bounds__(256) void k_cvt_w2(
    const float* __restrict__ w2, __hip_bfloat16* __restrict__ w2b)
{
    int idx = blockIdx.x*256 + threadIdx.x;   // 65536 total
    w2b[idx] = __float2bfloat16(w2[idx]);
}

// ---------------- K5: depthwise 3x3 + GELU + FFN2 (MFMA) + b2 + residual ----------------
// grid 1024: tile = 4 rows x 64 cols (256 pixels), all 128 out-channels, K=512.
__global__ __launch_bounds__(256) void k_ffn2_mfma(
    const __hip_bfloat16* __restrict__ h1,   // [B][512][HW] bf16
    const __hip_bfloat16* __restrict__ w2b,  // [128][512] bf16
    const float* __restrict__ dwf, const float* __restrict__ dwb,
    const float* __restrict__ b2, float* __restrict__ out)
{
    __shared__ __hip_bfloat16 halo[32*6*68];   // [c][r][68], 26112 B
    __shared__ __hip_bfloat16 sconv[256*40];   // [pix][40], 20480 B (k-major per pixel)
    const int t = threadIdx.x;
    const int lane = t & 63, w = t >> 6;
    const int blk = blockIdx.x;                // 1024 = 4 b * 64 rowtiles * 4 coltiles
    const int b    = blk >> 8;
    const int rb   = blk & 255;
    const int row0 = (rb >> 2) * 4;
    const int x0   = (rb & 3) * 64;
    const __hip_bfloat16* h1b = h1 + (size_t)b*512*HW;

    f32x4 acc[8][4];
    #pragma unroll
    for (int mt = 0; mt < 8; ++mt)
        #pragma unroll
        for (int nt = 0; nt < 4; ++nt)
            acc[mt][nt] = (f32x4){0.f, 0.f, 0.f, 0.f};

    const int l15 = lane & 15;
    const int q4  = (lane >> 4) * 4;
    const int ko  = (lane >> 4) * 8;

    for (int cc = 0; cc < 16; ++cc) {
        const int cbase = cc * 32;
        // --- stage halo: 32ch x 6 rows x 34 uints (pairs of bf16), zero-padded edges
        #pragma unroll
        for (int i = 0; i < 26; ++i) {
            int idx = t + i*256;
            if (idx < 6528) {
                int c   = idx / 204;           // 204 = 6*34
                int rem = idx - c*204;
                int r   = rem / 34;
                int u   = rem - r*34;
                int y   = row0 + r - 1;
                int xg  = x0 - 2 + u*2;
                unsigned int v = 0u;
                if ((unsigned)y < 256u && (unsigned)xg < 256u)
                    v = *(const unsigned int*)(h1b + (size_t)(cbase + c)*HW + y*256 + xg);
                *(unsigned int*)(&halo[c*408 + r*68 + u*2]) = v;
            }
        }
        __syncthreads();
        // --- depthwise conv + dwb + gelu -> sconv[pix][32] bf16 (wave w = tile row w)
        #pragma unroll
        for (int cp = 0; cp < 16; ++cp) {
            float rr[2];
            #pragma unroll
            for (int h = 0; h < 2; ++h) {
                const int c = cp*2 + h;
                const float* dwc = dwf + (size_t)(cbase + c)*9;
                float s = dwb[cbase + c];
                const __hip_bfloat16* hr = &halo[c*408 + w*68 + lane + 1];
                #pragma unroll
                for (int r = 0; r < 3; ++r) {
                    s = fmaf(__bfloat162float(hr[r*68 + 0]), dwc[r*3+0], s);
                    s = fmaf(__bfloat162float(hr[r*68 + 1]), dwc[r*3+1], s);
                    s = fmaf(__bfloat162float(hr[r*68 + 2]), dwc[r*3+2], s);
                }
                rr[h] = geluf(s);
            }
            __hip_bfloat162 pk;
            pk.x = __float2bfloat16(rr[0]);
            pk.y = __float2bfloat16(rr[1]);
            *(__hip_bfloat162*)(&sconv[t*40 + cp*2]) = pk;
        }
        __syncthreads();
        // --- MFMA: D[128 out][64 pix(wave)] += W2[:, cbase:+32] x sconv
        bf16x8 bfrag[4];
        #pragma unroll
        for (int nt = 0; nt < 4; ++nt) {
            const int pix = w*64 + nt*16 + l15;
            bfrag[nt] = *(const bf16x8*)((const short*)sconv + pix*40 + ko);
        }
        #pragma unroll
        for (int mt = 0; mt < 8; ++mt) {
            const int m = mt*16 + l15;
            bf16x8 afrag = *(const bf16x8*)((const short*)w2b + m*512 + cbase + ko);
            #pragma unroll
            for (int nt = 0; nt < 4; ++nt)
                acc[mt][nt] = __builtin_amdgcn_mfma_f32_16x16x32_bf16(afrag, bfrag[nt], acc[mt][nt], 0, 0, 0);
        }
    }
    // --- epilogue: + b2 + residual
    float* ob = out + (size_t)b*CHW;
    #pragma unroll
    for (int mt = 0; mt < 8; ++mt) {
        #pragma unroll
        for (int nt = 0; nt < 4; ++nt) {
            const int pix = w*64 + nt*16 + l15;
            const int y = row0 + (pix >> 6);
            const int xg = x0 + (pix & 63);
            #pragma unroll
            for (int r = 0; r < 4; ++r) {
                const int o = mt*16 + q4 + r;
                const size_t off = (size_t)o*HW + (size_t)y*256 + xg;
                ob[off] = acc[mt][nt][r] + b2[o] + ob[off];
            }
        }
    }
}

extern "C" void kernel_launch(void* const* d_in, const int* in_sizes, int n_in,
                              void* d_out, int out_size, void* d_ws, size_t ws_size,
                              hipStream_t stream) {
    const float* x      = (const float*)d_in[0];
    const float* l0     = (const float*)d_in[1];
    const float* n1w    = (const float*)d_in[2];
    const float* n1b    = (const float*)d_in[3];
    const float* n2w    = (const float*)d_in[4];
    const float* n2b    = (const float*)d_in[5];
    const float* qkv_w  = (const float*)d_in[6];
    const float* gate_w = (const float*)d_in[7];
    const float* gate_b = (const float*)d_in[8];
    const float* proj_w = (const float*)d_in[9];
    const float* proj_b = (const float*)d_in[10];
    const float* ffn_w1 = (const float*)d_in[11];
    const float* ffn_b1 = (const float*)d_in[12];
    const float* ffn_dw = (const float*)d_in[13];
    const float* ffn_dwb= (const float*)d_in[14];
    const float* ffn_w2 = (const float*)d_in[15];
    const float* ffn_b2 = (const float*)d_in[16];

    float* out = (float*)d_out;
    float* qkv = (float*)d_ws;                       // [B,384,HW] f32 = 384 MiB
    __hip_bfloat16* h1 = (__hip_bfloat16*)d_ws;      // [B,512,HW] bf16 = 256 MiB (reuses qkv region)
    __hip_bfloat16* w2b = (__hip_bfloat16*)((char*)d_ws + 268435456); // 128 KiB, after h1

    k_ln_qkv<<<dim3(4096, 3), dim3(256), 0, stream>>>(x, l0, n1w, n1b, qkv_w, gate_w, gate_b, qkv);
    k_attn  <<<dim3(4096, 8), dim3(64),  0, stream>>>(qkv, out);
    k_cvt_w2<<<dim3(256),     dim3(256), 0, stream>>>(ffn_w2, w2b);   // qkv dead after k_attn
    k_proj  <<<dim3(4096, 1), dim3(256), 0, stream>>>(x, proj_w, proj_b, out);
    k_ffn1  <<<dim3(4096, 4), dim3(256), 0, stream>>>(out, n2w, n2b, ffn_w1, ffn_b1, h1);
    k_ffn2_mfma<<<dim3(1024), dim3(256), 0, stream>>>(h1, w2b, ffn_dw, ffn_dwb, ffn_b2, out);
}

// Round 3
// 2316.148 us; speedup vs baseline: 4.1924x; 2.7392x over previous
//
#include <hip/hip_runtime.h>
#include <hip/hip_bf16.h>

#define HW   65536
#define CHW  (128*65536)

typedef __attribute__((ext_vector_type(8))) short bf16x8;
typedef __attribute__((ext_vector_type(4))) float f32x4;

__device__ __forceinline__ float geluf(float v){
    // tanh-form GELU, overflow-safe. max abs dev from exact erf-GELU ~1e-3.
    float u = 0.7978845608028654f * v * (1.f + 0.044715f*v*v);
    float e = __expf(2.f*u);
    float th = 1.f - 2.f/(e+1.f);
    return 0.5f*v*(1.f+th);
}

__device__ __forceinline__ float sigmoidf_(float z){
    return 1.f / (1.f + __expf(-z));
}

// ---------------- K0: f32 -> bf16 weight conversion ----------------
__global__ __launch_bounds__(256) void k_cvt(
    const float* __restrict__ src, __hip_bfloat16* __restrict__ dst, int n)
{
    int i = blockIdx.x*256 + threadIdx.x;
    if (i < n) dst[i] = __float2bfloat16(src[i]);
}

// ---------------- K1: LN1 + QKV GEMM (MFMA) + gate(q) -> qkv bf16 ----------------
// grid 1024, block 256. Tile: 256 contiguous pixels, K=128, M=384 in 3 chunks.
__global__ __launch_bounds__(256,2) void k_ln_qkv_mfma(
    const float* __restrict__ x, const float* __restrict__ l0,
    const float* __restrict__ n1w, const float* __restrict__ n1b,
    const __hip_bfloat16* __restrict__ qkvw, const float* __restrict__ gate_w,
    const float* __restrict__ gate_b, __hip_bfloat16* __restrict__ qkvb)
{
    __shared__ short sxb[256*130];      // [px][128 bf16 + 2 pad] = 65 dwords/row (odd -> conflict-free)
    const int t = threadIdx.x;
    const int lane = t & 63, w = t >> 6;
    const int l15 = lane & 15, q4 = (lane >> 4) * 4;
    const int pbase = blockIdx.x * 256;
    const int b = pbase >> 16;
    const int hw0 = pbase & 65535;
    const float* xb = x + (size_t)b*CHW + hw0 + t;   // this thread's pixel column
    unsigned* srow = (unsigned*)sxb + t*65;

    // pass A: LN stats + raw bf16 stash (thread t owns pixel t -> no reduction)
    float s1 = 0.f, s2 = 0.f;
    #pragma unroll 8
    for (int c0 = 0; c0 < 128; c0 += 2) {
        float v0 = xb[(size_t)c0*HW];
        float v1 = xb[(size_t)(c0+1)*HW];
        s1 += v0 + v1; s2 += v0*v0 + v1*v1;
        __hip_bfloat162 pk = __float22bfloat162_rn(make_float2(v0, v1));
        srow[c0>>1] = *(unsigned*)&pk;
    }
    const float mean = s1 * 0.0078125f;
    const float rstd = rsqrtf(s2*0.0078125f - mean*mean + 1e-6f);
    // pass B: normalize in place (own row, no sync needed yet)
    #pragma unroll 8
    for (int j = 0; j < 64; ++j) {
        unsigned u = srow[j];
        float v0 = __uint_as_float(u << 16);
        float v1 = __uint_as_float(u & 0xffff0000u);
        const int c = j*2;
        v0 = (v0 - mean)*rstd*n1w[c]   + n1b[c];
        v1 = (v1 - mean)*rstd*n1w[c+1] + n1b[c+1];
        __hip_bfloat162 pk = __float22bfloat162_rn(make_float2(v0, v1));
        srow[j] = *(unsigned*)&pk;
    }
    __syncthreads();

    // B fragments (activations, k-major per pixel)
    const unsigned* sw = (const unsigned*)sxb;
    bf16x8 bfrag[4][4];
    #pragma unroll
    for (int nt = 0; nt < 4; ++nt) {
        const int px = w*64 + nt*16 + l15;
        #pragma unroll
        for (int kc = 0; kc < 4; ++kc) {
            const int base = px*65 + kc*16 + (lane>>4)*4;
            unsigned r0 = sw[base], r1 = sw[base+1], r2 = sw[base+2], r3 = sw[base+3];
            union { unsigned u[4]; bf16x8 v; } tmp;
            tmp.u[0]=r0; tmp.u[1]=r1; tmp.u[2]=r2; tmp.u[3]=r3;
            bfrag[nt][kc] = tmp.v;
        }
    }
    float lv[4];
    #pragma unroll
    for (int nt = 0; nt < 4; ++nt)
        lv[nt] = l0[(size_t)b*HW + hw0 + w*64 + nt*16 + l15];

    const short* wq = (const short*)qkvw;
    for (int oz = 0; oz < 3; ++oz) {
        f32x4 acc[8][4];
        #pragma unroll
        for (int mt = 0; mt < 8; ++mt)
            #pragma unroll
            for (int nt = 0; nt < 4; ++nt)
                acc[mt][nt] = (f32x4){0.f,0.f,0.f,0.f};
        #pragma unroll
        for (int mt = 0; mt < 8; ++mt) {
            const int m = oz*128 + mt*16 + l15;
            #pragma unroll
            for (int kc = 0; kc < 4; ++kc) {
                bf16x8 af = *(const bf16x8*)(wq + m*128 + kc*32 + (lane>>4)*8);
                #pragma unroll
                for (int nt = 0; nt < 4; ++nt)
                    acc[mt][nt] = __builtin_amdgcn_mfma_f32_16x16x32_bf16(af, bfrag[nt][kc], acc[mt][nt], 0, 0, 0);
            }
        }
        __hip_bfloat16* ob = qkvb + ((size_t)b*384 + oz*128)*HW + hw0;
        if (oz == 0) {
            #pragma unroll
            for (int mt = 0; mt < 8; ++mt)
                #pragma unroll
                for (int nt = 0; nt < 4; ++nt) {
                    const int px = w*64 + nt*16 + l15;
                    #pragma unroll
                    for (int r = 0; r < 4; ++r) {
                        const int o = mt*16 + q4 + r;
                        const float g = sigmoidf_(lv[nt]*gate_w[o] + gate_b[o]);
                        ob[(size_t)o*HW + px] = __float2bfloat16(acc[mt][nt][r]*g);
                    }
                }
        } else {
            #pragma unroll
            for (int mt = 0; mt < 8; ++mt)
                #pragma unroll
                for (int nt = 0; nt < 4; ++nt) {
                    const int px = w*64 + nt*16 + l15;
                    #pragma unroll
                    for (int r = 0; r < 4; ++r) {
                        const int o = mt*16 + q4 + r;
                        ob[(size_t)o*HW + px] = __float2bfloat16(acc[mt][nt][r]);
                    }
                }
        }
    }
}

// ---------------- K2: windowed attention (bf16 qkv in, f32 out) ----------------
__global__ __launch_bounds__(64) void k_attn(
    const __hip_bfloat16* __restrict__ qkv, float* __restrict__ attn_out)
{
    __shared__ float sk[64*17];
    __shared__ float sv[64*17];
    const int t = threadIdx.x;
    const int win = blockIdx.x;
    const int head = blockIdx.y;
    const int b = win >> 10;
    const int wi = win & 1023;
    const int wy = wi >> 5, wx = wi & 31;
    const int ty = t >> 3, tx = t & 7;
    const int y = wy*8 + ty, xx = wx*8 + tx;
    const size_t hw = (size_t)y*256 + xx;
    const __hip_bfloat16* qb = qkv + (size_t)b*384*HW + (size_t)head*16*HW + hw;
    const __hip_bfloat16* kb = qb + (size_t)128*HW;
    const __hip_bfloat16* vb = qb + (size_t)256*HW;
    float qr[16];
    #pragma unroll
    for (int d = 0; d < 16; ++d) {
        qr[d]       = __bfloat162float(qb[(size_t)d*HW]);
        sk[t*17+d]  = __bfloat162float(kb[(size_t)d*HW]);
        sv[t*17+d]  = __bfloat162float(vb[(size_t)d*HW]);
    }
    __syncthreads();
    float sc[64];
    float m = -1e30f;
    #pragma unroll
    for (int kt = 0; kt < 64; ++kt) {
        float dot = 0.f;
        #pragma unroll
        for (int d = 0; d < 16; ++d) dot = fmaf(qr[d], sk[kt*17+d], dot);
        dot *= 0.25f;
        sc[kt] = dot;
        m = fmaxf(m, dot);
    }
    float ssum = 0.f;
    #pragma unroll
    for (int kt = 0; kt < 64; ++kt) { float e = __expf(sc[kt]-m); sc[kt] = e; ssum += e; }
    const float rs = 1.f / ssum;
    float o[16];
    #pragma unroll
    for (int d = 0; d < 16; ++d) o[d] = 0.f;
    #pragma unroll
    for (int kt = 0; kt < 64; ++kt) {
        const float p = sc[kt];
        #pragma unroll
        for (int d = 0; d < 16; ++d) o[d] = fmaf(p, sv[kt*17+d], o[d]);
    }
    float* ob = attn_out + (size_t)b*CHW + (size_t)head*16*HW + hw;
    #pragma unroll
    for (int d = 0; d < 16; ++d) ob[(size_t)d*HW] = o[d]*rs;
}

// ---------------- K3: proj (MFMA) + bias + shortcut, in-place on d_out ----------------
__global__ __launch_bounds__(256,2) void k_proj_mfma(
    const float* __restrict__ x, const __hip_bfloat16* __restrict__ projw,
    const float* __restrict__ proj_b, float* __restrict__ out)
{
    __shared__ short sxb[256*130];
    const int t = threadIdx.x;
    const int lane = t & 63, w = t >> 6;
    const int l15 = lane & 15, q4 = (lane >> 4) * 4;
    const int pbase = blockIdx.x * 256;
    const int b = pbase >> 16;
    const int hw0 = pbase & 65535;
    const float* ab = out + (size_t)b*CHW + hw0 + t;
    unsigned* srow = (unsigned*)sxb + t*65;
    #pragma unroll 8
    for (int c0 = 0; c0 < 128; c0 += 2) {
        float v0 = ab[(size_t)c0*HW];
        float v1 = ab[(size_t)(c0+1)*HW];
        __hip_bfloat162 pk = __float22bfloat162_rn(make_float2(v0, v1));
        srow[c0>>1] = *(unsigned*)&pk;
    }
    __syncthreads();
    const unsigned* sw = (const unsigned*)sxb;
    bf16x8 bfrag[4][4];
    #pragma unroll
    for (int nt = 0; nt < 4; ++nt) {
        const int px = w*64 + nt*16 + l15;
        #pragma unroll
        for (int kc = 0; kc < 4; ++kc) {
            const int base = px*65 + kc*16 + (lane>>4)*4;
            union { unsigned u[4]; bf16x8 v; } tmp;
            tmp.u[0]=sw[base]; tmp.u[1]=sw[base+1]; tmp.u[2]=sw[base+2]; tmp.u[3]=sw[base+3];
            bfrag[nt][kc] = tmp.v;
        }
    }
    f32x4 acc[8][4];
    #pragma unroll
    for (int mt = 0; mt < 8; ++mt)
        #pragma unroll
        for (int nt = 0; nt < 4; ++nt)
            acc[mt][nt] = (f32x4){0.f,0.f,0.f,0.f};
    const short* wp = (const short*)projw;
    #pragma unroll
    for (int mt = 0; mt < 8; ++mt) {
        const int m = mt*16 + l15;
        #pragma unroll
        for (int kc = 0; kc < 4; ++kc) {
            bf16x8 af = *(const bf16x8*)(wp + m*128 + kc*32 + (lane>>4)*8);
            #pragma unroll
            for (int nt = 0; nt < 4; ++nt)
                acc[mt][nt] = __builtin_amdgcn_mfma_f32_16x16x32_bf16(af, bfrag[nt][kc], acc[mt][nt], 0, 0, 0);
        }
    }
    const float* xb = x + (size_t)b*CHW + hw0;
    float* ob = out + (size_t)b*CHW + hw0;
    #pragma unroll
    for (int mt = 0; mt < 8; ++mt)
        #pragma unroll
        for (int nt = 0; nt < 4; ++nt) {
            const int px = w*64 + nt*16 + l15;
            #pragma unroll
            for (int r = 0; r < 4; ++r) {
                const int o = mt*16 + q4 + r;
                ob[(size_t)o*HW + px] = acc[mt][nt][r] + proj_b[o] + xb[(size_t)o*HW + px];
            }
        }
}

// ---------------- K4: LN2 + FFN1 (MFMA) + bias + GELU -> h1 bf16 ----------------
__global__ __launch_bounds__(256,2) void k_ffn1_mfma(
    const float* __restrict__ out, const float* __restrict__ n2w, const float* __restrict__ n2b,
    const __hip_bfloat16* __restrict__ w1, const float* __restrict__ b1,
    __hip_bfloat16* __restrict__ h1)
{
    __shared__ short sxb[256*130];
    const int t = threadIdx.x;
    const int lane = t & 63, w = t >> 6;
    const int l15 = lane & 15, q4 = (lane >> 4) * 4;
    const int pbase = blockIdx.x * 256;
    const int b = pbase >> 16;
    const int hw0 = pbase & 65535;
    const float* xb = out + (size_t)b*CHW + hw0 + t;
    unsigned* srow = (unsigned*)sxb + t*65;
    float s1 = 0.f, s2 = 0.f;
    #pragma unroll 8
    for (int c0 = 0; c0 < 128; c0 += 2) {
        float v0 = xb[(size_t)c0*HW];
        float v1 = xb[(size_t)(c0+1)*HW];
        s1 += v0 + v1; s2 += v0*v0 + v1*v1;
        __hip_bfloat162 pk = __float22bfloat162_rn(make_float2(v0, v1));
        srow[c0>>1] = *(unsigned*)&pk;
    }
    const float mean = s1 * 0.0078125f;
    const float rstd = rsqrtf(s2*0.0078125f - mean*mean + 1e-6f);
    #pragma unroll 8
    for (int j = 0; j < 64; ++j) {
        unsigned u = srow[j];
        float v0 = __uint_as_float(u << 16);
        float v1 = __uint_as_float(u & 0xffff0000u);
        const int c = j*2;
        v0 = (v0 - mean)*rstd*n2w[c]   + n2b[c];
        v1 = (v1 - mean)*rstd*n2w[c+1] + n2b[c+1];
        __hip_bfloat162 pk = __float22bfloat162_rn(make_float2(v0, v1));
        srow[j] = *(unsigned*)&pk;
    }
    __syncthreads();
    const unsigned* sw = (const unsigned*)sxb;
    bf16x8 bfrag[4][4];
    #pragma unroll
    for (int nt = 0; nt < 4; ++nt) {
        const int px = w*64 + nt*16 + l15;
        #pragma unroll
        for (int kc = 0; kc < 4; ++kc) {
            const int base = px*65 + kc*16 + (lane>>4)*4;
            union { unsigned u[4]; bf16x8 v; } tmp;
            tmp.u[0]=sw[base]; tmp.u[1]=sw[base+1]; tmp.u[2]=sw[base+2]; tmp.u[3]=sw[base+3];
            bfrag[nt][kc] = tmp.v;
        }
    }
    const short* w1s = (const short*)w1;
    __hip_bfloat16* hb = h1 + (size_t)b*512*HW + hw0;
    for (int mc = 0; mc < 4; ++mc) {
        f32x4 acc[8][4];
        #pragma unroll
        for (int mt = 0; mt < 8; ++mt)
            #pragma unroll
            for (int nt = 0; nt < 4; ++nt)
                acc[mt][nt] = (f32x4){0.f,0.f,0.f,0.f};
        #pragma unroll
        for (int mt = 0; mt < 8; ++mt) {
            const int m = mc*128 + mt*16 + l15;
            #pragma unroll
            for (int kc = 0; kc < 4; ++kc) {
                bf16x8 af = *(const bf16x8*)(w1s + m*128 + kc*32 + (lane>>4)*8);
                #pragma unroll
                for (int nt = 0; nt < 4; ++nt)
                    acc[mt][nt] = __builtin_amdgcn_mfma_f32_16x16x32_bf16(af, bfrag[nt][kc], acc[mt][nt], 0, 0, 0);
            }
        }
        #pragma unroll
        for (int mt = 0; mt < 8; ++mt)
            #pragma unroll
            for (int nt = 0; nt < 4; ++nt) {
                const int px = w*64 + nt*16 + l15;
                #pragma unroll
                for (int r = 0; r < 4; ++r) {
                    const int o = mc*128 + mt*16 + q4 + r;
                    const float v = geluf(acc[mt][nt][r] + b1[o]);
                    hb[(size_t)o*HW + px] = __float2bfloat16(v);
                }
            }
    }
}

// ---------------- K5: depthwise 3x3 + GELU + FFN2 (MFMA) + b2 + residual ----------------
__global__ __launch_bounds__(256) void k_ffn2_mfma(
    const __hip_bfloat16* __restrict__ h1,
    const __hip_bfloat16* __restrict__ w2b,
    const float* __restrict__ dwf, const float* __restrict__ dwb,
    const float* __restrict__ b2, float* __restrict__ out)
{
    __shared__ __hip_bfloat16 halo[32*6*68];
    __shared__ __hip_bfloat16 sconv[256*40];
    const int t = threadIdx.x;
    const int lane = t & 63, w = t >> 6;
    const int blk = blockIdx.x;
    const int b    = blk >> 8;
    const int rb   = blk & 255;
    const int row0 = (rb >> 2) * 4;
    const int x0   = (rb & 3) * 64;
    const __hip_bfloat16* h1b = h1 + (size_t)b*512*HW;

    f32x4 acc[8][4];
    #pragma unroll
    for (int mt = 0; mt < 8; ++mt)
        #pragma unroll
        for (int nt = 0; nt < 4; ++nt)
            acc[mt][nt] = (f32x4){0.f, 0.f, 0.f, 0.f};

    const int l15 = lane & 15;
    const int q4  = (lane >> 4) * 4;
    const int ko  = (lane >> 4) * 8;

    for (int cc = 0; cc < 16; ++cc) {
        const int cbase = cc * 32;
        #pragma unroll
        for (int i = 0; i < 26; ++i) {
            int idx = t + i*256;
            if (idx < 6528) {
                int c   = idx / 204;
                int rem = idx - c*204;
                int r   = rem / 34;
                int u   = rem - r*34;
                int y   = row0 + r - 1;
                int xg  = x0 - 2 + u*2;
                unsigned int v = 0u;
                if ((unsigned)y < 256u && (unsigned)xg < 256u)
                    v = *(const unsigned int*)(h1b + (size_t)(cbase + c)*HW + y*256 + xg);
                *(unsigned int*)(&halo[c*408 + r*68 + u*2]) = v;
            }
        }
        __syncthreads();
        #pragma unroll
        for (int cp = 0; cp < 16; ++cp) {
            float rr[2];
            #pragma unroll
            for (int h = 0; h < 2; ++h) {
                const int c = cp*2 + h;
                const float* dwc = dwf + (size_t)(cbase + c)*9;
                float s = dwb[cbase + c];
                const __hip_bfloat16* hr = &halo[c*408 + w*68 + lane + 1];
                #pragma unroll
                for (int r = 0; r < 3; ++r) {
                    s = fmaf(__bfloat162float(hr[r*68 + 0]), dwc[r*3+0], s);
                    s = fmaf(__bfloat162float(hr[r*68 + 1]), dwc[r*3+1], s);
                    s = fmaf(__bfloat162float(hr[r*68 + 2]), dwc[r*3+2], s);
                }
                rr[h] = geluf(s);
            }
            __hip_bfloat162 pk;
            pk.x = __float2bfloat16(rr[0]);
            pk.y = __float2bfloat16(rr[1]);
            *(__hip_bfloat162*)(&sconv[t*40 + cp*2]) = pk;
        }
        __syncthreads();
        bf16x8 bfrag[4];
        #pragma unroll
        for (int nt = 0; nt < 4; ++nt) {
            const int pix = w*64 + nt*16 + l15;
            bfrag[nt] = *(const bf16x8*)((const short*)sconv + pix*40 + ko);
        }
        #pragma unroll
        for (int mt = 0; mt < 8; ++mt) {
            const int m = mt*16 + l15;
            bf16x8 afrag = *(const bf16x8*)((const short*)w2b + m*512 + cbase + ko);
            #pragma unroll
            for (int nt = 0; nt < 4; ++nt)
                acc[mt][nt] = __builtin_amdgcn_mfma_f32_16x16x32_bf16(afrag, bfrag[nt], acc[mt][nt], 0, 0, 0);
        }
    }
    float* ob = out + (size_t)b*CHW;
    #pragma unroll
    for (int mt = 0; mt < 8; ++mt) {
        #pragma unroll
        for (int nt = 0; nt < 4; ++nt) {
            const int pix = w*64 + nt*16 + l15;
            const int y = row0 + (pix >> 6);
            const int xg = x0 + (pix & 63);
            #pragma unroll
            for (int r = 0; r < 4; ++r) {
                const int o = mt*16 + q4 + r;
                const size_t off = (size_t)o*HW + (size_t)y*256 + xg;
                ob[off] = acc[mt][nt][r] + b2[o] + ob[off];
            }
        }
    }
}

extern "C" void kernel_launch(void* const* d_in, const int* in_sizes, int n_in,
                              void* d_out, int out_size, void* d_ws, size_t ws_size,
                              hipStream_t stream) {
    const float* x      = (const float*)d_in[0];
    const float* l0     = (const float*)d_in[1];
    const float* n1w    = (const float*)d_in[2];
    const float* n1b    = (const float*)d_in[3];
    const float* n2w    = (const float*)d_in[4];
    const float* n2b    = (const float*)d_in[5];
    const float* qkv_w  = (const float*)d_in[6];
    const float* gate_w = (const float*)d_in[7];
    const float* gate_b = (const float*)d_in[8];
    const float* proj_w = (const float*)d_in[9];
    const float* proj_b = (const float*)d_in[10];
    const float* ffn_w1 = (const float*)d_in[11];
    const float* ffn_b1 = (const float*)d_in[12];
    const float* ffn_dw = (const float*)d_in[13];
    const float* ffn_dwb= (const float*)d_in[14];
    const float* ffn_w2 = (const float*)d_in[15];
    const float* ffn_b2 = (const float*)d_in[16];

    float* out = (float*)d_out;
    // ws layout: [0,192MiB) qkv bf16 (later aliased by h1 bf16 [0,256MiB));
    //            [256MiB, +384KiB) bf16 weights.
    __hip_bfloat16* qkvb = (__hip_bfloat16*)d_ws;
    __hip_bfloat16* h1   = (__hip_bfloat16*)d_ws;
    char* wbase = (char*)d_ws + 268435456;
    __hip_bfloat16* qkvw_b = (__hip_bfloat16*)(wbase);
    __hip_bfloat16* projw_b= (__hip_bfloat16*)(wbase + 98304);
    __hip_bfloat16* w1b    = (__hip_bfloat16*)(wbase + 131072);
    __hip_bfloat16* w2b    = (__hip_bfloat16*)(wbase + 262144);

    k_cvt<<<dim3(192), dim3(256), 0, stream>>>(qkv_w, qkvw_b, 49152);
    k_cvt<<<dim3(64),  dim3(256), 0, stream>>>(proj_w, projw_b, 16384);
    k_cvt<<<dim3(256), dim3(256), 0, stream>>>(ffn_w1, w1b, 65536);
    k_cvt<<<dim3(256), dim3(256), 0, stream>>>(ffn_w2, w2b, 65536);

    k_ln_qkv_mfma<<<dim3(1024), dim3(256), 0, stream>>>(x, l0, n1w, n1b, qkvw_b, gate_w, gate_b, qkvb);
    k_attn       <<<dim3(4096, 8), dim3(64), 0, stream>>>(qkvb, out);
    k_proj_mfma  <<<dim3(1024), dim3(256), 0, stream>>>(x, projw_b, proj_b, out);
    k_ffn1_mfma  <<<dim3(1024), dim3(256), 0, stream>>>(out, n2w, n2b, w1b, ffn_b1, h1);
    k_ffn2_mfma  <<<dim3(1024), dim3(256), 0, stream>>>(h1, w2b, ffn_dw, ffn_dwb, ffn_b2, out);
}